// Round 2
// baseline (12174.133 us; speedup 1.0000x reference)
//
#include <hip/hip_runtime.h>
#include <hip/hip_bf16.h>

// NeuronConvNet: 7x grouped conv1d (K=15, SAME) + leaky_relu, then 1x1 root conv.
// B=16, T=4096. Layer chain:
//   leaf : x[:,0:1280]  groups=64, in/g=20, out/g=8  -> h1 (512 ch)
//   int0 : h1           groups=32, in/g=16, out/g=8  -> h2 (256 ch)
//   br   : [h2 | x[:,1280:1536]] per-group concat (8+8), groups=32 -> h3 (256 ch)
//   int1..int4: groups 16,8,4,2, in/g=16, out/g=8 -> 128,64,32,16 ch
//   root : 1x1 conv, 16ch -> 1ch, no activation
// Round 2: all-fp32 I/O (R1's NaN proved inputs are fp32, not bf16).

#define T_LEN   4096
#define KK      15
#define PAD     7
#define TW      512          // t-tile per block
#define NT      64           // threads per block (1 wave)
#define TPT     8            // t per thread: NT*TPT == TW
#define SW      (TW + 16)    // LDS row stride (floats), 16B-aligned, >= TW+14

// SPLIT=false: input rows from inA, ch = g*IPG + r
// SPLIT=true : r<8 from inA (ch=g*8+r), r>=8 from inX (ch=xbase+g*8+r-8)
template <int IPG, bool SPLIT>
__global__ __launch_bounds__(NT) void gconv_kernel(
    const float* __restrict__ inA, int cinA,
    const float* __restrict__ inX, int cinX, int xbase,
    const float* __restrict__ W,
    const float* __restrict__ bias,
    float* __restrict__ out, int Cout)
{
    __shared__ float s_in[IPG * SW];
    const int tile = blockIdx.x;
    const int oc   = blockIdx.y;
    const int b    = blockIdx.z;
    const int g    = oc >> 3;           // 8 outputs per group in every conv layer
    const int tid  = threadIdx.x;
    const int t0g  = tile * TW - PAD;

    // ---- stage input tile (fp32 in LDS), zero-padded at T boundaries ----
    for (int r = 0; r < IPG; ++r) {
        for (int p = tid; p < TW + 2 * PAD; p += NT) {
            const int gt = t0g + p;
            float v = 0.f;
            if (gt >= 0 && gt < T_LEN) {
                if constexpr (!SPLIT) {
                    const int ch = g * IPG + r;
                    v = inA[((size_t)b * cinA + ch) * T_LEN + gt];
                } else {
                    if (r < 8) {
                        const int ch = g * 8 + r;
                        v = inA[((size_t)b * cinA + ch) * T_LEN + gt];
                    } else {
                        const int ch = xbase + g * 8 + (r - 8);
                        v = inX[((size_t)b * cinX + ch) * T_LEN + gt];
                    }
                }
            }
            s_in[r * SW + p] = v;
        }
    }
    __syncthreads();

    // ---- compute: each thread does TPT consecutive t via sliding window ----
    float acc[TPT];
    const float bv = bias[oc];
#pragma unroll
    for (int j = 0; j < TPT; ++j) acc[j] = bv;

    const int tl = tid * TPT;   // local t of first output
    for (int ic = 0; ic < IPG; ++ic) {
        float xw[TPT + KK - 1];             // 22 floats
        const float* row = &s_in[ic * SW + tl];
#pragma unroll
        for (int q = 0; q < (TPT + KK - 1) / 4; ++q)       // 5x ds_read_b128
            *(float4*)&xw[q * 4] = *(const float4*)&row[q * 4];
        xw[20] = row[20];
        xw[21] = row[21];
        const float* wr = &W[((size_t)oc * IPG + ic) * KK];
#pragma unroll
        for (int k = 0; k < KK; ++k) {
            const float wv = wr[k];
#pragma unroll
            for (int j = 0; j < TPT; ++j) acc[j] += wv * xw[k + j];
        }
    }

    // ---- leaky relu + store (two float4) ----
#pragma unroll
    for (int j = 0; j < TPT; ++j) {
        const float v = acc[j];
        acc[j] = v > 0.f ? v : 0.01f * v;
    }
    const size_t ob = ((size_t)b * Cout + oc) * T_LEN + tile * TW + tl;
    *(float4*)&out[ob]     = *(const float4*)&acc[0];
    *(float4*)&out[ob + 4] = *(const float4*)&acc[4];
}

// 1x1 conv over 16 channels, no activation, fp32 output
__global__ __launch_bounds__(256) void root_kernel(
    const float* __restrict__ h,
    const float* __restrict__ W,
    const float* __restrict__ bias,
    float* __restrict__ out)
{
    const int idx = blockIdx.x * 256 + threadIdx.x;   // b*T + t
    const int b = idx >> 12;
    const int t = idx & (T_LEN - 1);
    float acc = bias[0];
#pragma unroll
    for (int ic = 0; ic < 16; ++ic)
        acc += W[ic] * h[((size_t)b * 16 + ic) * T_LEN + t];
    out[idx] = acc;
}

extern "C" void kernel_launch(void* const* d_in, const int* in_sizes, int n_in,
                              void* d_out, int out_size, void* d_ws, size_t ws_size,
                              hipStream_t stream)
{
    const float* x      = (const float*)d_in[0];
    const float* W_leaf = (const float*)d_in[1];
    const float* b_leaf = (const float*)d_in[2];
    const float* W_int0 = (const float*)d_in[3];
    const float* b_int0 = (const float*)d_in[4];
    const float* W_br   = (const float*)d_in[5];
    const float* b_br   = (const float*)d_in[6];
    const float* W_int1 = (const float*)d_in[7];
    const float* b_int1 = (const float*)d_in[8];
    const float* W_int2 = (const float*)d_in[9];
    const float* b_int2 = (const float*)d_in[10];
    const float* W_int3 = (const float*)d_in[11];
    const float* b_int3 = (const float*)d_in[12];
    const float* W_int4 = (const float*)d_in[13];
    const float* b_int4 = (const float*)d_in[14];
    const float* W_root = (const float*)d_in[15];
    const float* b_root = (const float*)d_in[16];

    // fp32 ping-pong workspace (192 MiB total):
    //   buf0: up to 512 ch  (128 MiB)
    //   buf1: up to 256 ch  ( 64 MiB)
    float* buf0 = (float*)d_ws;
    float* buf1 = buf0 + (size_t)16 * 512 * 4096;

    const dim3 blk(NT);
    const int tiles = T_LEN / TW;  // 8

    // leaf: x (1536ch, base 0, ch=g*20+r) -> buf0 (512 ch)
    gconv_kernel<20, false><<<dim3(tiles, 512, 16), blk, 0, stream>>>(
        x, 1536, nullptr, 0, 0, W_leaf, b_leaf, buf0, 512);
    // int0: buf0 (512) -> buf1 (256)
    gconv_kernel<16, false><<<dim3(tiles, 256, 16), blk, 0, stream>>>(
        buf0, 512, nullptr, 0, 0, W_int0, b_int0, buf1, 256);
    // br: [buf1 (256) | x ch1280..1535] -> buf0 (256)
    gconv_kernel<16, true><<<dim3(tiles, 256, 16), blk, 0, stream>>>(
        buf1, 256, x, 1536, 1280, W_br, b_br, buf0, 256);
    // int1: buf0 (256) -> buf1 (128)
    gconv_kernel<16, false><<<dim3(tiles, 128, 16), blk, 0, stream>>>(
        buf0, 256, nullptr, 0, 0, W_int1, b_int1, buf1, 128);
    // int2: buf1 (128) -> buf0 (64)
    gconv_kernel<16, false><<<dim3(tiles, 64, 16), blk, 0, stream>>>(
        buf1, 128, nullptr, 0, 0, W_int2, b_int2, buf0, 64);
    // int3: buf0 (64) -> buf1 (32)
    gconv_kernel<16, false><<<dim3(tiles, 32, 16), blk, 0, stream>>>(
        buf0, 64, nullptr, 0, 0, W_int3, b_int3, buf1, 32);
    // int4: buf1 (32) -> buf0 (16)
    gconv_kernel<16, false><<<dim3(tiles, 16, 16), blk, 0, stream>>>(
        buf1, 32, nullptr, 0, 0, W_int4, b_int4, buf0, 16);
    // root: buf0 (16) -> d_out fp32 (16*4096)
    root_kernel<<<dim3((16 * T_LEN) / 256), dim3(256), 0, stream>>>(
        buf0, W_root, b_root, (float*)d_out);
}

// Round 3
// 1373.780 us; speedup vs baseline: 8.8618x; 8.8618x over previous
//
#include <hip/hip_runtime.h>
#include <hip/hip_bf16.h>

// NeuronConvNet: 7x grouped conv1d (K=15, SAME) + leaky_relu, then 1x1 root conv.
// B=16, T=4096.
//   leaf : x[:,0:1280]  groups=64, in/g=20, out/g=8  -> h1 (512 ch)
//   int0 : h1           groups=32, in/g=16, out/g=8  -> h2 (256 ch)
//   br   : [h2 | x[:,1280:1536]] per-group concat (8+8), groups=32 -> h3 (256 ch)
//   int1..int4: groups 16,8,4,2, in/g=16, out/g=8 -> 128,64,32,16 ch
//   root : 1x1 conv, 16ch -> 1ch, no activation
// Round 3: block = (b, group, t-tile), 256 threads, all 8 oc per block.
//   - chunk-transposed LDS layout kills the 16-way bank conflicts of R2
//   - each thread: 2 oc x 8 t, shared 22-float window per input channel

#define T_LEN   4096
#define KK      15
#define PAD     7
#define TW      512                 // t-tile per block
#define WIN     (TW + 2 * PAD)      // 526 staged elements per row
#define CH      68                  // chunk-dim stride (66 chunks used, +2 pad)
#define ROWSZ   (8 * CH)            // 544 floats per LDS row

// LDS layout: row ic, element p (0..WIN-1) lives at ic*ROWSZ + (p&7)*CH + (p>>3).
// Compute reads (fixed q, varying lane l): addr = ic*ROWSZ + (q&7)*CH + (q>>3) + l
//   -> stride-1 across lanes -> conflict-free.

// SPLIT=false: input rows from inA, ch = g*IPG + r
// SPLIT=true : r<8 from inA (ch=g*8+r), r>=8 from inX (ch=xbase+g*8+r-8)
template <int IPG, bool SPLIT>
__global__ __launch_bounds__(256) void gconv_kernel(
    const float* __restrict__ inA, int cinA,
    const float* __restrict__ inX, int cinX, int xbase,
    const float* __restrict__ W,
    const float* __restrict__ bias,
    float* __restrict__ out, int Cout)
{
    __shared__ float s_in[IPG * ROWSZ];
    const int tile = blockIdx.x;
    const int g    = blockIdx.y;
    const int b    = blockIdx.z;
    const int tid  = threadIdx.x;
    const int t0g  = tile * TW - PAD;

    // ---- stage input tile into transposed-chunk LDS layout ----
    for (int r = 0; r < IPG; ++r) {
        const float* src;
        if constexpr (!SPLIT) {
            src = inA + ((size_t)b * cinA + (g * IPG + r)) * T_LEN;
        } else {
            src = (r < 8)
                ? inA + ((size_t)b * cinA + (g * 8 + r)) * T_LEN
                : inX + ((size_t)b * cinX + (xbase + g * 8 + (r - 8))) * T_LEN;
        }
        for (int p = tid; p < WIN; p += 256) {
            const int gt = t0g + p;
            const float v = (gt >= 0 && gt < T_LEN) ? src[gt] : 0.f;
            s_in[r * ROWSZ + (p & 7) * CH + (p >> 3)] = v;
        }
    }
    __syncthreads();

    // ---- compute: thread = (oc pair, t-chunk); 2 oc x 8 consecutive t ----
    const int l   = tid & 63;                                   // t-chunk
    const int ocp = __builtin_amdgcn_readfirstlane(tid >> 6);   // 0..3 (wave-uniform)
    const int oc0 = g * 8 + ocp * 2;

    float acc0[8], acc1[8];
    const float bv0 = bias[oc0], bv1 = bias[oc0 + 1];
#pragma unroll
    for (int j = 0; j < 8; ++j) { acc0[j] = bv0; acc1[j] = bv1; }

    for (int ic = 0; ic < IPG; ++ic) {
        float xw[22];
#pragma unroll
        for (int q = 0; q < 22; ++q)
            xw[q] = s_in[ic * ROWSZ + (q & 7) * CH + (q >> 3) + l];
        const float* w0 = W + ((size_t)oc0 * IPG + ic) * KK;
        const float* w1 = w0 + (size_t)IPG * KK;
#pragma unroll
        for (int k = 0; k < KK; ++k) {
            const float a0 = w0[k], a1 = w1[k];
#pragma unroll
            for (int j = 0; j < 8; ++j) {
                acc0[j] += a0 * xw[k + j];
                acc1[j] += a1 * xw[k + j];
            }
        }
    }

    // ---- leaky relu + store (2 oc x 2 float4) ----
#pragma unroll
    for (int j = 0; j < 8; ++j) {
        acc0[j] = acc0[j] > 0.f ? acc0[j] : 0.01f * acc0[j];
        acc1[j] = acc1[j] > 0.f ? acc1[j] : 0.01f * acc1[j];
    }
    const size_t o0 = ((size_t)b * Cout + oc0) * T_LEN + tile * TW + 8 * l;
    *(float4*)&out[o0]             = *(const float4*)&acc0[0];
    *(float4*)&out[o0 + 4]         = *(const float4*)&acc0[4];
    *(float4*)&out[o0 + T_LEN]     = *(const float4*)&acc1[0];
    *(float4*)&out[o0 + T_LEN + 4] = *(const float4*)&acc1[4];
}

// 1x1 conv over 16 channels, no activation, fp32 output
__global__ __launch_bounds__(256) void root_kernel(
    const float* __restrict__ h,
    const float* __restrict__ W,
    const float* __restrict__ bias,
    float* __restrict__ out)
{
    const int idx = blockIdx.x * 256 + threadIdx.x;   // b*T + t
    const int b = idx >> 12;
    const int t = idx & (T_LEN - 1);
    float acc = bias[0];
#pragma unroll
    for (int ic = 0; ic < 16; ++ic)
        acc += W[ic] * h[((size_t)b * 16 + ic) * T_LEN + t];
    out[idx] = acc;
}

extern "C" void kernel_launch(void* const* d_in, const int* in_sizes, int n_in,
                              void* d_out, int out_size, void* d_ws, size_t ws_size,
                              hipStream_t stream)
{
    const float* x      = (const float*)d_in[0];
    const float* W_leaf = (const float*)d_in[1];
    const float* b_leaf = (const float*)d_in[2];
    const float* W_int0 = (const float*)d_in[3];
    const float* b_int0 = (const float*)d_in[4];
    const float* W_br   = (const float*)d_in[5];
    const float* b_br   = (const float*)d_in[6];
    const float* W_int1 = (const float*)d_in[7];
    const float* b_int1 = (const float*)d_in[8];
    const float* W_int2 = (const float*)d_in[9];
    const float* b_int2 = (const float*)d_in[10];
    const float* W_int3 = (const float*)d_in[11];
    const float* b_int3 = (const float*)d_in[12];
    const float* W_int4 = (const float*)d_in[13];
    const float* b_int4 = (const float*)d_in[14];
    const float* W_root = (const float*)d_in[15];
    const float* b_root = (const float*)d_in[16];

    // fp32 ping-pong workspace (192 MiB total)
    float* buf0 = (float*)d_ws;
    float* buf1 = buf0 + (size_t)16 * 512 * 4096;

    const int tiles = T_LEN / TW;  // 8
    const dim3 blk(256);

    // leaf: x (ch=g*20+r, row-stride 1536) -> buf0 (512 ch)
    gconv_kernel<20, false><<<dim3(tiles, 64, 16), blk, 0, stream>>>(
        x, 1536, nullptr, 0, 0, W_leaf, b_leaf, buf0, 512);
    // int0: buf0 (512) -> buf1 (256)
    gconv_kernel<16, false><<<dim3(tiles, 32, 16), blk, 0, stream>>>(
        buf0, 512, nullptr, 0, 0, W_int0, b_int0, buf1, 256);
    // br: [buf1 (256) | x ch1280..1535] -> buf0 (256)
    gconv_kernel<16, true><<<dim3(tiles, 32, 16), blk, 0, stream>>>(
        buf1, 256, x, 1536, 1280, W_br, b_br, buf0, 256);
    // int1: buf0 (256) -> buf1 (128)
    gconv_kernel<16, false><<<dim3(tiles, 16, 16), blk, 0, stream>>>(
        buf0, 256, nullptr, 0, 0, W_int1, b_int1, buf1, 128);
    // int2: buf1 (128) -> buf0 (64)
    gconv_kernel<16, false><<<dim3(tiles, 8, 16), blk, 0, stream>>>(
        buf1, 128, nullptr, 0, 0, W_int2, b_int2, buf0, 64);
    // int3: buf0 (64) -> buf1 (32)
    gconv_kernel<16, false><<<dim3(tiles, 4, 16), blk, 0, stream>>>(
        buf0, 64, nullptr, 0, 0, W_int3, b_int3, buf1, 32);
    // int4: buf1 (32) -> buf0 (16)
    gconv_kernel<16, false><<<dim3(tiles, 2, 16), blk, 0, stream>>>(
        buf1, 32, nullptr, 0, 0, W_int4, b_int4, buf0, 16);
    // root: buf0 (16) -> d_out fp32 (16*4096)
    root_kernel<<<dim3((16 * T_LEN) / 256), dim3(256), 0, stream>>>(
        buf0, W_root, b_root, (float*)d_out);
}

// Round 4
// 1007.360 us; speedup vs baseline: 12.0852x; 1.3637x over previous
//
#include <hip/hip_runtime.h>
#include <hip/hip_bf16.h>

// NeuronConvNet, Round 4: bf16 MFMA implicit-GEMM grouped conv.
// Per 16x16x32 MFMA: M = 8 oc x 2 t-shifts (shifted-weight rows),
// K = ic*16 + k' (K=15 padded to 16), N = 16 cols at t-stride 2.
//   A[s*8+oc][ic*16+k'] = W[oc][ic][k'-s]   (0 outside [0,15))
//   B[(ic,k')][n]       = X[ic][t0 + 2n + k' - 7]
//   C[s*8+oc][n]        = O[oc][t0 + 2n + s]
// Intermediates are bf16; x/weights fp32 in, converted during staging.

#define T_LEN 4096
#define KK    15
#define TW    256            // output t-tile per block (16 tiles)
#define XS    272            // LDS X row stride (bf16), 544 B: 16B multiple
#define XV    270            // staged valid length: TW + 14 halo

typedef __attribute__((ext_vector_type(8))) short short8;
typedef __attribute__((ext_vector_type(4))) float v4f;

#define MODE_F32   0
#define MODE_BF16  1
#define MODE_SPLIT 2

// MODE_F32  : inA fp32, ch = g*IPG + r            (leaf; reads x)
// MODE_BF16 : inA bf16, ch = g*IPG + r            (int layers)
// MODE_SPLIT: r<8 from inA bf16 (ch=g*8+r), r>=8 from inX fp32 (ch=xbase+g*8+r-8)
template <int IPG, int MODE>
__global__ __launch_bounds__(256) void gconv_mfma(
    const void*  __restrict__ inA_, int cinA,
    const float* __restrict__ inX,  int cinX, int xbase,
    const float* __restrict__ W,
    const float* __restrict__ bias,
    __hip_bfloat16* __restrict__ out, int Cout)
{
    constexpr int KD = IPG * 16;   // padded K dim (320 or 256)
    constexpr int NM = KD / 32;    // MFMAs per output tile (10 or 8)

    __shared__ __align__(16) __hip_bfloat16 s_x[IPG * XS];
    __shared__ __align__(16) __hip_bfloat16 s_a[16 * KD];
    __shared__ __align__(16) __hip_bfloat16 s_c[8 * TW];

    const int tile = blockIdx.x, g = blockIdx.y, b = blockIdx.z;
    const int tid  = threadIdx.x;
    const int t_org = tile * TW - 7;      // LDS row origin in global t

    // ---- build shifted-weight A matrix in LDS (bf16) ----
    for (int i = tid; i < 16 * KD; i += 256) {
        const int m  = i / KD, kk = i % KD;
        const int ic = kk >> 4, kp = kk & 15;
        const int s  = m >> 3,  oc = m & 7;
        const int k  = kp - s;
        const float wv = (k >= 0 && k < KK)
            ? W[((size_t)(g * 8 + oc) * IPG + ic) * KK + k] : 0.f;
        s_a[i] = __float2bfloat16(wv);
    }
    // ---- stage X tile (bf16) with halo, zero-padded at T bounds ----
    for (int i = tid; i < IPG * XV; i += 256) {
        const int r = i / XV, p = i % XV;
        const int gt = t_org + p;
        __hip_bfloat16 v = __float2bfloat16(0.f);
        if (gt >= 0 && gt < T_LEN) {
            if constexpr (MODE == MODE_F32) {
                v = __float2bfloat16(
                    ((const float*)inA_)[((size_t)b * cinA + g * IPG + r) * T_LEN + gt]);
            } else if constexpr (MODE == MODE_BF16) {
                v = ((const __hip_bfloat16*)inA_)[((size_t)b * cinA + g * IPG + r) * T_LEN + gt];
            } else {
                if (r < 8)
                    v = ((const __hip_bfloat16*)inA_)[((size_t)b * cinA + g * 8 + r) * T_LEN + gt];
                else
                    v = __float2bfloat16(
                        inX[((size_t)b * cinX + xbase + g * 8 + (r - 8)) * T_LEN + gt]);
            }
        }
        s_x[r * XS + p] = v;
    }
    __syncthreads();

    const int l = tid & 63;           // lane
    const int wv_ = tid >> 6;         // wave 0..3 (uniform)
    const int n = l & 15, q = l >> 4; // MFMA col / lane-quad

    // ---- preload A fragments: lane holds A[m=n][k = j*32 + q*8 + 0..7] ----
    short8 fa[NM];
#pragma unroll
    for (int j = 0; j < NM; ++j)
        fa[j] = *(const short8*)&s_a[n * KD + j * 32 + q * 8];

    // bias per C reg: row m = q*4 + r -> oc = m&7
    float bv[4];
#pragma unroll
    for (int r = 0; r < 4; ++r) bv[r] = bias[g * 8 + ((q * 4 + r) & 7)];

    // ---- 2 chunks of 32 t per wave: full K chain each ----
    for (int c = 0; c < 2; ++c) {
        const int co = (wv_ * 2 + c) * 32;   // chunk t-offset within tile
        v4f acc = {bv[0], bv[1], bv[2], bv[3]};
#pragma unroll
        for (int j = 0; j < NM; ++j) {
            const int ic  = j * 2 + (q >> 1);
            const int idx = co + 2 * n + ((q & 1) * 8);    // even -> 4B aligned
            const unsigned int* bp = (const unsigned int*)&s_x[ic * XS + idx];
            union { unsigned int u[4]; short8 v; } bb;
            bb.u[0] = bp[0]; bb.u[1] = bp[1]; bb.u[2] = bp[2]; bb.u[3] = bp[3];
            acc = __builtin_amdgcn_mfma_f32_16x16x32_bf16(fa[j], bb.v, acc, 0, 0, 0);
        }
        // leaky-relu + scatter into linear [oc][t] staging (bf16)
#pragma unroll
        for (int r = 0; r < 4; ++r) {
            float v = acc[r];
            v = v > 0.f ? v : 0.01f * v;
            const int m = q * 4 + r, oc = m & 7, s = m >> 3;
            s_c[oc * TW + co + 2 * n + s] = __float2bfloat16(v);
        }
    }
    __syncthreads();

    // ---- coalesced bf16 store: 8 rows x 256 cols, 16B per thread ----
    {
        const int oc = tid >> 5, col = (tid & 31) * 8;
        const short8 vvv = *(const short8*)&s_c[oc * TW + col];
        *(short8*)(out + ((size_t)b * Cout + g * 8 + oc) * T_LEN + tile * TW + col) = vvv;
    }
}

// 1x1 conv over 16 bf16 channels -> fp32 out, no activation
__global__ __launch_bounds__(256) void root_kernel(
    const __hip_bfloat16* __restrict__ h,
    const float* __restrict__ W,
    const float* __restrict__ bias,
    float* __restrict__ out)
{
    const int idx = blockIdx.x * 256 + threadIdx.x;   // b*T + t
    const int b = idx >> 12;
    const int t = idx & (T_LEN - 1);
    float acc = bias[0];
#pragma unroll
    for (int ic = 0; ic < 16; ++ic)
        acc += W[ic] * __bfloat162float(h[((size_t)b * 16 + ic) * T_LEN + t]);
    out[idx] = acc;
}

extern "C" void kernel_launch(void* const* d_in, const int* in_sizes, int n_in,
                              void* d_out, int out_size, void* d_ws, size_t ws_size,
                              hipStream_t stream)
{
    const float* x      = (const float*)d_in[0];
    const float* W_leaf = (const float*)d_in[1];
    const float* b_leaf = (const float*)d_in[2];
    const float* W_int0 = (const float*)d_in[3];
    const float* b_int0 = (const float*)d_in[4];
    const float* W_br   = (const float*)d_in[5];
    const float* b_br   = (const float*)d_in[6];
    const float* W_int1 = (const float*)d_in[7];
    const float* b_int1 = (const float*)d_in[8];
    const float* W_int2 = (const float*)d_in[9];
    const float* b_int2 = (const float*)d_in[10];
    const float* W_int3 = (const float*)d_in[11];
    const float* b_int3 = (const float*)d_in[12];
    const float* W_int4 = (const float*)d_in[13];
    const float* b_int4 = (const float*)d_in[14];
    const float* W_root = (const float*)d_in[15];
    const float* b_root = (const float*)d_in[16];

    // bf16 ping-pong: bufA up to 512 ch (67 MB), bufB up to 256 ch (33.5 MB)
    __hip_bfloat16* bufA = (__hip_bfloat16*)d_ws;
    __hip_bfloat16* bufB = bufA + (size_t)16 * 512 * 4096;

    const int tiles = T_LEN / TW;  // 16
    const dim3 blk(256);

    // leaf: x fp32 (ch=g*20+r) -> bufA (512 ch bf16)
    gconv_mfma<20, MODE_F32><<<dim3(tiles, 64, 16), blk, 0, stream>>>(
        x, 1536, nullptr, 0, 0, W_leaf, b_leaf, bufA, 512);
    // int0: bufA (512) -> bufB (256)
    gconv_mfma<16, MODE_BF16><<<dim3(tiles, 32, 16), blk, 0, stream>>>(
        bufA, 512, nullptr, 0, 0, W_int0, b_int0, bufB, 256);
    // br: [bufB (256) | x ch1280..1535 fp32] -> bufA (256)
    gconv_mfma<16, MODE_SPLIT><<<dim3(tiles, 32, 16), blk, 0, stream>>>(
        bufB, 256, x, 1536, 1280, W_br, b_br, bufA, 256);
    // int1: bufA (256) -> bufB (128)
    gconv_mfma<16, MODE_BF16><<<dim3(tiles, 16, 16), blk, 0, stream>>>(
        bufA, 256, nullptr, 0, 0, W_int1, b_int1, bufB, 128);
    // int2: bufB (128) -> bufA (64)
    gconv_mfma<16, MODE_BF16><<<dim3(tiles, 8, 16), blk, 0, stream>>>(
        bufB, 128, nullptr, 0, 0, W_int2, b_int2, bufA, 64);
    // int3: bufA (64) -> bufB (32)
    gconv_mfma<16, MODE_BF16><<<dim3(tiles, 4, 16), blk, 0, stream>>>(
        bufA, 64, nullptr, 0, 0, W_int3, b_int3, bufB, 32);
    // int4: bufB (32) -> bufA (16)
    gconv_mfma<16, MODE_BF16><<<dim3(tiles, 2, 16), blk, 0, stream>>>(
        bufB, 32, nullptr, 0, 0, W_int4, b_int4, bufA, 16);
    // root: bufA (16 ch bf16) -> d_out fp32
    root_kernel<<<dim3((16 * T_LEN) / 256), dim3(256), 0, stream>>>(
        bufA, W_root, b_root, (float*)d_out);
}